// Round 18
// baseline (109.574 us; speedup 1.0000x reference)
//
#include <hip/hip_runtime.h>
#include <math.h>

#define B_   8
#define C_   256
#define NH_  8
#define N_   1024
#define LOG2E    1.4426950408889634f

typedef __attribute__((ext_vector_type(8))) short bf16x8;
typedef __attribute__((ext_vector_type(4))) float f32x4;
typedef __attribute__((ext_vector_type(2))) float f32x2;
typedef unsigned short u16;
typedef unsigned int u32;

#define AS1 __attribute__((address_space(1)))
#define AS3 __attribute__((address_space(3)))

__device__ __forceinline__ f32x4 mfma16(bf16x8 a, bf16x8 b, f32x4 c) {
    return __builtin_amdgcn_mfma_f32_16x16x32_bf16(a, b, c, 0, 0, 0);
}
__device__ __forceinline__ u32 bf16r(float x) {     // RNE f32->bf16 bits
    u32 b = __float_as_uint(x);
    return (b + 0x7fffu + ((b >> 16) & 1u)) >> 16;
}
// exact algebra: tanh(softplus(x)) = (e^2+2e)/(e^2+2e+2), e = exp(x)
__device__ __forceinline__ float mish_fast(float x) {
    float e  = __builtin_amdgcn_exp2f(fminf(x, 30.f) * LOG2E);
    float nm = e * (e + 2.f);
    return x * nm * __builtin_amdgcn_rcpf(nm + 2.f);
}
__device__ __forceinline__ f32x2 splat2(float v) { return (f32x2){v, v}; }
// deg-11 truncated Chebyshev of f(c)=e^{1-acos(c)/pi}, Estrin form:
// p(c) = P(c^2) + c*Q(c^2). Evaluated ONCE per element; f cached as bf16
// pairs (the same rounding Ps stores); rowsums accumulate full-precision f.
__device__ __forceinline__ f32x2 fexp_poly2(f32x2 c) {
    c = __builtin_elementwise_min(
            __builtin_elementwise_max(c, splat2(-0.999999f)), splat2(0.999999f));
    f32x2 u = c * c;
    f32x2 p = __builtin_elementwise_fma(splat2(1.7809920f), u, splat2(-3.7571968f));
    f32x2 q = __builtin_elementwise_fma(splat2(6.3713280f), u, splat2(-15.1427584f));
    p = __builtin_elementwise_fma(p, u, splat2(2.8140000f));
    q = __builtin_elementwise_fma(q, u, splat2(13.1518784f));
    p = __builtin_elementwise_fma(p, u, splat2(-0.8122592f));
    q = __builtin_elementwise_fma(q, u, splat2(-4.8903712f));
    p = __builtin_elementwise_fma(p, u, splat2(0.1705120f));
    q = __builtin_elementwise_fma(q, u, splat2(0.8441120f));
    p = __builtin_elementwise_fma(p, u, splat2(1.6473155f));
    q = __builtin_elementwise_fma(q, u, splat2(0.4936541f));
    return __builtin_elementwise_fma(c, q, p);
}

// ---------- Kernel 1: grouped conv + BN + mish (+normalize/pack), split ----
// blocks 0..255: q | 256..511: k | 512..767: v | 768..831: f_w -> bf16.
__global__ __launch_bounds__(256) void qkvpack_kernel(
    const float* __restrict__ x,
    const float* __restrict__ qw, const float* __restrict__ qb2,
    const float* __restrict__ qs, const float* __restrict__ qbeta,
    const float* __restrict__ kw, const float* __restrict__ kb2,
    const float* __restrict__ ks, const float* __restrict__ kbeta,
    const float* __restrict__ vw, const float* __restrict__ vb2,
    const float* __restrict__ vs, const float* __restrict__ vbeta,
    uint4* __restrict__ qpk, uint4* __restrict__ kpk, u16* __restrict__ vbf,
    const float* __restrict__ fw, u16* __restrict__ wbf)
{
    int blk = blockIdx.x;
    if (blk >= 768) {               // f_w -> bf16
        int id = (blk - 768) * 1024 + threadIdx.x;
#pragma unroll
        for (int j = 0; j < 4; ++j) { int p = id + j * 256; wbf[p] = (u16)bf16r(fw[p]); }
        return;
    }
    int type = blk >> 8;            // 0=q, 1=k, 2=v
    int sub = blk & 255;
    int nt = sub & 3, g = (sub >> 2) & 7, b = sub >> 5;
    int n = nt * 256 + threadIdx.x;
    int bh = b * 8 + g;
    const float* xp = x + ((size_t)b * C_ + g * 32) * N_ + n;
    float xv[32];
#pragma unroll
    for (int i = 0; i < 32; ++i) xv[i] = xp[(size_t)i * N_];

    const float *w, *bb, *sc, *bt;
    if (type == 0)      { w = qw; bb = qb2; sc = qs; bt = qbeta; }
    else if (type == 1) { w = kw; bb = kb2; sc = ks; bt = kbeta; }
    else                { w = vw; bb = vb2; sc = vs; bt = vbeta; }

    float y[32];
#pragma unroll
    for (int co = 0; co < 32; ++co) {
        int cg = g * 32 + co;
        float acc = 0.f;
#pragma unroll
        for (int i = 0; i < 32; ++i)
            acc = fmaf(xv[i], w[cg * 32 + i], acc);
        // INV_TEMP omitted for q: normalized below, scale cancels in cosine
        y[co] = mish_fast(sc[cg] * (acc + bb[cg]) + bt[cg]);
    }

    if (type == 2) {                // v: bf16 [bh][d][n]
#pragma unroll
        for (int co = 0; co < 32; ++co)
            vbf[((size_t)bh * 32 + co) * N_ + n] = (u16)bf16r(y[co]);
        return;
    }
    float s2 = 0.f;
#pragma unroll
    for (int d = 0; d < 32; ++d) s2 = fmaf(y[d], y[d], s2);
    float inv = __builtin_amdgcn_rsqf(fmaxf(s2, 1e-24f));
    u32 wp[16];
#pragma unroll
    for (int d = 0; d < 16; ++d)
        wp[d] = bf16r(y[2 * d] * inv) | (bf16r(y[2 * d + 1] * inv) << 16);
    uint4* dst = (type == 0 ? qpk : kpk) + ((size_t)bh * N_ + n) * 4;
#pragma unroll
    for (int j = 0; j < 4; ++j)
        dst[j] = make_uint4(wp[4 * j], wp[4 * j + 1], wp[4 * j + 2], wp[4 * j + 3]);
}

// ---------------- Kernel 2: attention (single pass, m-split wave pairs) ----
// R11 structure with the CORRECT launch bound: (512, 2) -> 128-VGPR cap so
// the fc[64] cache lives in registers (R11's (512,4) forced 64 VGPR and
// spilled to scratch -- 168 MB of WRITE_SIZE). Waves 0-3: m in [0,512);
// waves 4-7: m in [512,1024) for the SAME 64 rows. Per chunk: T14 reg-stage
// K+V, QK MFMA, poly ONCE, cache bf16(f) in fc[64], write Ps, unnormalized
// PV. Then cross-wave rowsum exchange -> rinv; register-only am pass;
// epilogue combines O halves and scales by rinv.
__global__ __launch_bounds__(512, 2) void attn_kernel(
    const u16* __restrict__ qpk, const u16* __restrict__ kpk,
    const u16* __restrict__ vbf,
    u16* __restrict__ aout_bt, float* __restrict__ ampart)
{
    __shared__ __align__(16) u16 Kl[1024 * 8];      // 16 KB [half][j][m][8]
    __shared__ __align__(16) u16 Vl[1024 * 8];      // 16 KB [half][d][mgran]
    __shared__ __align__(16) u16 Ps[8][16 * 136];   // 34 KB, rows padded 272B
    __shared__ __align__(16) float amW[N_];         // 4 KB
    __shared__ __align__(16) float rsX[8][16];      // 512 B rowsum exchange

    const int tid  = threadIdx.x;
    const int wave = tid >> 6, lane = tid & 63;
    const int l15 = lane & 15, lg = lane >> 4;
    const int half = wave >> 2;                     // m-half this wave owns
    const int w3 = wave & 3;                        // row-tile within block
    // XCD-aware bijective swizzle: 1024 = 8 XCD x 128
    const int swz = (blockIdx.x & 7) * 128 + (blockIdx.x >> 3);
    const int itile = swz & 15, bh = swz >> 4;
    const int h = bh & 7, bidx = bh >> 3;
    const int i0 = itile * 64;

    const char* ksrc = (const char*)(kpk + (size_t)bh * N_ * 32);
    const char* vsrc = (const char*)(vbf + (size_t)bh * 32 * N_);
    const char* qsrc = (const char*)(qpk + (size_t)bh * N_ * 32);

    amW[tid] = 0.f; amW[512 + tid] = 0.f;

    // staging coords: thread stages K granules {tid (low), tid+512 (high)}
    const size_t koffL = (size_t)(tid & 127) * 64 + (size_t)(tid >> 7) * 16;
    const size_t koffH = koffL + 512 * 64;
    const int vd = tid >> 4, vg = tid & 15;
    const size_t voffL = (size_t)vd * 2048 + (size_t)((vg ^ (vd & 7)) << 4);
    const size_t voffH = voffL + 1024;              // +512 m = +1024 B

    // Q frag: row = i0 + w3*16 + l15, d-chunk lg (held for whole kernel)
    bf16x8 aq = *(const bf16x8*)(qsrc + (size_t)(i0 + w3 * 16 + l15) * 64 + lg * 16);

    const char* kfb = (const char*)Kl + half * 8192 + lg * 2048 + l15 * 16;
    const char* vfb = (const char*)Vl + half * 8192 + l15 * 256;
    const int   vkey = l15 & 7;
    char*       psw = (char*)&Ps[wave][0] + lg * 1088 + l15 * 2;
    const char* pab = (const char*)&Ps[wave][0] + l15 * 272 + lg * 16;

    u32 fc[64];                     // bf16(f) pair cache, static indexing only
    f32x2 rsL = {0.f, 0.f}, rsH = {0.f, 0.f};
    f32x4 o0 = {0.f, 0.f, 0.f, 0.f}, o1 = {0.f, 0.f, 0.f, 0.f};

    uint4 kregL = *(const uint4*)(ksrc + koffL);    // preload chunk 0
    uint4 kregH = *(const uint4*)(ksrc + koffH);
    uint4 vregL = *(const uint4*)(vsrc + voffL);
    uint4 vregH = *(const uint4*)(vsrc + voffH);

    // ================= single pass: 4 chunks of 128 m per half =============
#pragma unroll
    for (int ch = 0; ch < 4; ++ch) {
        *(uint4*)((char*)Kl + tid * 16)         = kregL;  // waits vmcnt (auto)
        *(uint4*)((char*)Kl + (512 + tid) * 16) = kregH;
        *(uint4*)((char*)Vl + tid * 16)         = vregL;
        *(uint4*)((char*)Vl + (512 + tid) * 16) = vregH;
        if (ch < 3) {                                     // issue next chunk
            kregL = *(const uint4*)(ksrc + (size_t)(ch + 1) * 8192 + koffL);
            kregH = *(const uint4*)(ksrc + (size_t)(ch + 1) * 8192 + koffH);
            vregL = *(const uint4*)(vsrc + (size_t)(ch + 1) * 256 + voffL);
            vregH = *(const uint4*)(vsrc + (size_t)(ch + 1) * 256 + voffH);
        }
        asm volatile("s_waitcnt lgkmcnt(0)" ::: "memory");
        __builtin_amdgcn_sched_barrier(0);
        __builtin_amdgcn_s_barrier();                     // no vmcnt drain
        __builtin_amdgcn_sched_barrier(0);

        // QK + poly (once) + fc cache + Ps write
#pragma unroll
        for (int t = 0; t < 8; ++t) {
            bf16x8 bk = *(const bf16x8*)(kfb + t * 256);
            f32x4 cf = {0.f, 0.f, 0.f, 0.f};
            cf = mfma16(aq, bk, cf);
            f32x2 fL = fexp_poly2((f32x2){cf[0], cf[1]});
            f32x2 fH = fexp_poly2((f32x2){cf[2], cf[3]});
            rsL += fL; rsH += fH;
            u32 r0 = bf16r(fL.x) | (bf16r(fL.y) << 16);
            u32 r1 = bf16r(fH.x) | (bf16r(fH.y) << 16);
            fc[ch * 16 + t * 2]     = r0;
            fc[ch * 16 + t * 2 + 1] = r1;
            *(u16*)(psw + 0 * 272 + t * 32) = (u16)r0;
            *(u16*)(psw + 1 * 272 + t * 32) = (u16)(r0 >> 16);
            *(u16*)(psw + 2 * 272 + t * 32) = (u16)r1;
            *(u16*)(psw + 3 * 272 + t * 32) = (u16)(r1 >> 16);
        }
        asm volatile("s_waitcnt lgkmcnt(0)" ::: "memory");  // own-wave Ps done
        __builtin_amdgcn_sched_barrier(0);
        // PV (unnormalized; rinv deferred to epilogue)
#pragma unroll
        for (int kss = 0; kss < 4; ++kss) {
            bf16x8 pa = *(const bf16x8*)(pab + kss * 64);
            const char* va = vfb + (((kss * 4 + lg) ^ vkey) << 4);
            bf16x8 v0 = *(const bf16x8*)va;
            bf16x8 v1 = *(const bf16x8*)(va + 4096);      // d = 16 + l15
            o0 = mfma16(pa, v0, o0);
            o1 = mfma16(pa, v1, o1);
        }
        asm volatile("s_waitcnt lgkmcnt(0)" ::: "memory");
        __builtin_amdgcn_sched_barrier(0);
        __builtin_amdgcn_s_barrier();                     // Kl/Vl free
        __builtin_amdgcn_sched_barrier(0);
    }

    // ---- rowsum: lane-reduce over l15 group, then cross-wave exchange ----
    float rr[4] = {rsL.x, rsL.y, rsH.x, rsH.y};
#pragma unroll
    for (int r = 0; r < 4; ++r) {
        float s = rr[r];
        s += __shfl_xor(s, 1); s += __shfl_xor(s, 2);
        s += __shfl_xor(s, 4); s += __shfl_xor(s, 8);
        rr[r] = s;                                  // half-range rowsum
    }
    if (l15 == 0) {
#pragma unroll
        for (int r = 0; r < 4; ++r) rsX[wave][lg * 4 + r] = rr[r];
    }
    __syncthreads();
    float rinv[4];
#pragma unroll
    for (int r = 0; r < 4; ++r)
        rinv[r] = __builtin_amdgcn_rcpf(rr[r] + rsX[wave ^ 4][lg * 4 + r]);
    f32x2 rinvL = {rinv[0], rinv[1]}, rinvH = {rinv[2], rinv[3]};

    // ---- am pass: register-only unpack of fc, column sums, atomics ----
    const int mbase = half * 512;
#pragma unroll
    for (int ch = 0; ch < 4; ++ch) {
#pragma unroll
        for (int t = 0; t < 8; ++t) {
            u32 r0 = fc[ch * 16 + t * 2];
            u32 r1 = fc[ch * 16 + t * 2 + 1];
            f32x2 fL = {__uint_as_float(r0 << 16), __uint_as_float(r0 & 0xffff0000u)};
            f32x2 fH = {__uint_as_float(r1 << 16), __uint_as_float(r1 & 0xffff0000u)};
            f32x2 cs2 = fL * rinvL;
            cs2 = __builtin_elementwise_fma(fH, rinvH, cs2);
            float csum = cs2.x + cs2.y;
            csum += __shfl_xor(csum, 16);
            csum += __shfl_xor(csum, 32);
            if (lane < 16) atomicAdd(&amW[mbase + ch * 128 + t * 16 + l15], csum);
        }
    }
    __syncthreads();   // amW complete; Ps region free for O-combine reuse

    // ---- epilogue: combine O halves via LDS, scale by rinv, store ----
    float* Obuf = (float*)Ps;                       // [64][33] f32 (padded)
    if (half == 1) {
#pragma unroll
        for (int r = 0; r < 4; ++r) {
            int row = w3 * 16 + lg * 4 + r;
            Obuf[row * 33 + l15]      = o0[r];
            Obuf[row * 33 + 16 + l15] = o1[r];
        }
    }
    __syncthreads();
    u16* oT = (u16*)((char*)Ps + 9216);             // [64][40] u16 (80B rows)
    if (half == 0) {
#pragma unroll
        for (int r = 0; r < 4; ++r) {
            int row = w3 * 16 + lg * 4 + r;
            float a0 = (o0[r] + Obuf[row * 33 + l15])      * rinv[r];
            float a1 = (o1[r] + Obuf[row * 33 + 16 + l15]) * rinv[r];
            oT[row * 40 + l15]      = (u16)bf16r(a0);
            oT[row * 40 + 16 + l15] = (u16)bf16r(a1);
        }
    }
    __syncthreads();
    if (tid < 256) {
        int row = tid >> 2, c4 = tid & 3;
        uint4 val = *(const uint4*)((const char*)oT + row * 80 + c4 * 16);
        int n = i0 + row;
        int g = h * 4 + c4;
        size_t dst = ((size_t)(bidx * N_ + n) << 9) + ((size_t)((g ^ (row & 7)) << 4));
        *(uint4*)((char*)aout_bt + dst) = val;
    }
    ampart[(size_t)swz * N_ + tid]       = amW[tid];
    ampart[(size_t)swz * N_ + 512 + tid] = amW[512 + tid];
}

// ---------- Kernel 3: fconv (MFMA) + mish + residual; blocks 256..263: am --
__global__ __launch_bounds__(256) void fconv_kernel(
    const u16* __restrict__ aout_bt, const u16* __restrict__ wbf,
    const float* __restrict__ x,
    const float* __restrict__ fs, const float* __restrict__ fb,
    const float* __restrict__ fbeta, float* __restrict__ y,
    const float* __restrict__ ampart, float* __restrict__ outAm)
{
    __shared__ __align__(16) u16 As[32 * 256];   // 16 KB [n][c] swizzled
    __shared__ float rmn[256], rmx[256];
    const int tid = threadIdx.x;

    if (blockIdx.x >= 256) {       // ---- attention-map reduce + normalize ----
        int b = blockIdx.x - 256;
        const float* base = ampart + (size_t)b * 128 * N_;
        float s[4] = {0.f, 0.f, 0.f, 0.f};
        for (int p = 0; p < 128; ++p) {
#pragma unroll
            for (int c2 = 0; c2 < 4; ++c2)
                s[c2] += base[(size_t)p * N_ + tid + 256 * c2];
        }
        float mn = fminf(fminf(s[0], s[1]), fminf(s[2], s[3]));
        float mx = fmaxf(fmaxf(s[0], s[1]), fmaxf(s[2], s[3]));
        rmn[tid] = mn; rmx[tid] = mx;
        __syncthreads();
        for (int off = 128; off >= 1; off >>= 1) {
            if (tid < off) {
                rmn[tid] = fminf(rmn[tid], rmn[tid + off]);
                rmx[tid] = fmaxf(rmx[tid], rmx[tid + off]);
            }
            __syncthreads();
        }
        mn = rmn[0]; mx = rmx[0];
        float inv = 1.f / (mx - mn);
#pragma unroll
        for (int c2 = 0; c2 < 4; ++c2)
            outAm[(size_t)b * N_ + tid + 256 * c2] = (s[c2] - mn) * inv;
        return;
    }

    const int wave = tid >> 6, lane = tid & 63;
    const int l15 = lane & 15, lg = lane >> 4;
    const int b  = blockIdx.x >> 5;
    const int n0 = (blockIdx.x & 31) * 32;

    const char* asrc = (const char*)aout_bt + ((size_t)(b * N_ + n0) << 9);
#pragma unroll
    for (int p = 0; p < 4; ++p) {
        int g = p * 256 + wave * 64 + lane;
        __builtin_amdgcn_global_load_lds(
            (const AS1 void*)(asrc + g * 16),
            (AS3 void*)((char*)As + ((p * 256 + wave * 64) << 4)), 16, 0, 0);
    }
    __syncthreads();

    f32x4 acc[4][2];
#pragma unroll
    for (int f = 0; f < 4; ++f)
#pragma unroll
        for (int fn = 0; fn < 2; ++fn) acc[f][fn] = (f32x4){0.f, 0.f, 0.f, 0.f};

    const int cobase = wave * 64;
#pragma unroll
    for (int kk = 0; kk < 8; ++kk) {
        bf16x8 af[2];
#pragma unroll
        for (int fn = 0; fn < 2; ++fn) {
            int nf = fn * 16 + l15;
            af[fn] = *(const bf16x8*)((const char*)As + nf * 512 +
                                      (((kk * 4 + lg) ^ (nf & 7)) << 4));
        }
#pragma unroll
        for (int f = 0; f < 4; ++f) {
            bf16x8 wf = *(const bf16x8*)(wbf + (size_t)(cobase + f * 16 + l15) * 256 + kk * 32 + lg * 8);
            acc[f][0] = mfma16(wf, af[0], acc[f][0]);
            acc[f][1] = mfma16(wf, af[1], acc[f][1]);
        }
    }

#pragma unroll
    for (int f = 0; f < 4; ++f) {
#pragma unroll
        for (int r = 0; r < 4; ++r) {
            int co = cobase + f * 16 + lg * 4 + r;
            float sc = fs[co], bb = fb[co], bt = fbeta[co];
#pragma unroll
            for (int fn = 0; fn < 2; ++fn) {
                int n = n0 + fn * 16 + l15;
                size_t oid = ((size_t)(b * C_ + co) << 10) + n;
                y[oid] = mish_fast(sc * (acc[f][fn][r] + bb) + bt) + x[oid];
            }
        }
    }
}

extern "C" void kernel_launch(void* const* d_in, const int* in_sizes, int n_in,
                              void* d_out, int out_size, void* d_ws, size_t ws_size,
                              hipStream_t stream)
{
    const float* x     = (const float*)d_in[0];
    const float* q_w   = (const float*)d_in[1];
    const float* q_b   = (const float*)d_in[2];
    const float* q_s   = (const float*)d_in[3];
    const float* q_be  = (const float*)d_in[4];
    const float* k_w   = (const float*)d_in[5];
    const float* k_b   = (const float*)d_in[6];
    const float* k_s   = (const float*)d_in[7];
    const float* k_be  = (const float*)d_in[8];
    const float* v_w   = (const float*)d_in[9];
    const float* v_b   = (const float*)d_in[10];
    const float* v_s   = (const float*)d_in[11];
    const float* v_be  = (const float*)d_in[12];
    const float* f_w   = (const float*)d_in[13];
    const float* f_b   = (const float*)d_in[14];
    const float* f_s   = (const float*)d_in[15];
    const float* f_be  = (const float*)d_in[16];

    float* y_out  = (float*)d_out;                        // (8,256,32,32)
    float* am_out = (float*)d_out + (size_t)B_ * C_ * N_; // (8,32,32)

    char* w = (char*)d_ws;
    u16*   qpk     = (u16*)w;    w += (size_t)B_ * NH_ * N_ * 64;    // 4 MB
    u16*   kpk     = (u16*)w;    w += (size_t)B_ * NH_ * N_ * 64;    // 4 MB
    u16*   vbf     = (u16*)w;    w += (size_t)B_ * C_ * N_ * 2;      // 4 MB
    u16*   aout_bt = (u16*)w;    w += (size_t)B_ * N_ * C_ * 2;      // 4 MB
    float* ampart  = (float*)w;  w += (size_t)B_ * NH_ * 16 * N_ * 4;// 4 MB
    u16*   wbf     = (u16*)w;                                        // 128 KB

    qkvpack_kernel<<<832, 256, 0, stream>>>(
        x, q_w, q_b, q_s, q_be, k_w, k_b, k_s, k_be,
        v_w, v_b, v_s, v_be, (uint4*)qpk, (uint4*)kpk, vbf, f_w, wbf);

    attn_kernel<<<B_ * NH_ * 16, 512, 0, stream>>>(
        qpk, kpk, vbf, aout_bt, ampart);

    fconv_kernel<<<264, 256, 0, stream>>>(
        aout_bt, wbf, x, f_s, f_b, f_be, y_out, ampart, am_out);
}

// Round 19
// 104.525 us; speedup vs baseline: 1.0483x; 1.0483x over previous
//
#include <hip/hip_runtime.h>
#include <math.h>

#define B_   8
#define C_   256
#define NH_  8
#define N_   1024
#define LOG2E    1.4426950408889634f

typedef __attribute__((ext_vector_type(8))) short bf16x8;
typedef __attribute__((ext_vector_type(4))) float f32x4;
typedef __attribute__((ext_vector_type(2))) float f32x2;
typedef unsigned short u16;
typedef unsigned int u32;

#define AS1 __attribute__((address_space(1)))
#define AS3 __attribute__((address_space(3)))

__device__ __forceinline__ f32x4 mfma16(bf16x8 a, bf16x8 b, f32x4 c) {
    return __builtin_amdgcn_mfma_f32_16x16x32_bf16(a, b, c, 0, 0, 0);
}
__device__ __forceinline__ u32 bf16r(float x) {     // RNE f32->bf16 bits
    u32 b = __float_as_uint(x);
    return (b + 0x7fffu + ((b >> 16) & 1u)) >> 16;
}
// exact algebra: tanh(softplus(x)) = (e^2+2e)/(e^2+2e+2), e = exp(x)
__device__ __forceinline__ float mish_fast(float x) {
    float e  = __builtin_amdgcn_exp2f(fminf(x, 30.f) * LOG2E);
    float nm = e * (e + 2.f);
    return x * nm * __builtin_amdgcn_rcpf(nm + 2.f);
}
__device__ __forceinline__ f32x2 splat2(float v) { return (f32x2){v, v}; }
// deg-11 truncated Chebyshev of f(c)=e^{1-acos(c)/pi}, Estrin form:
// p(c) = P(c^2) + c*Q(c^2) -- two independent chains (half the dep depth).
// Both sweeps share it, so P/rowsum systematics cancel.
__device__ __forceinline__ f32x2 fexp_poly2(f32x2 c) {
    c = __builtin_elementwise_min(
            __builtin_elementwise_max(c, splat2(-0.999999f)), splat2(0.999999f));
    f32x2 u = c * c;
    f32x2 p = __builtin_elementwise_fma(splat2(1.7809920f), u, splat2(-3.7571968f));
    f32x2 q = __builtin_elementwise_fma(splat2(6.3713280f), u, splat2(-15.1427584f));
    p = __builtin_elementwise_fma(p, u, splat2(2.8140000f));
    q = __builtin_elementwise_fma(q, u, splat2(13.1518784f));
    p = __builtin_elementwise_fma(p, u, splat2(-0.8122592f));
    q = __builtin_elementwise_fma(q, u, splat2(-4.8903712f));
    p = __builtin_elementwise_fma(p, u, splat2(0.1705120f));
    q = __builtin_elementwise_fma(q, u, splat2(0.8441120f));
    p = __builtin_elementwise_fma(p, u, splat2(1.6473155f));
    q = __builtin_elementwise_fma(q, u, splat2(0.4936541f));
    return __builtin_elementwise_fma(c, q, p);
}

// ---------- Kernel 1: grouped conv + BN + mish (+normalize/pack), split ----
// blocks 0..255: q | 256..511: k | 512..767: v | 768..831: f_w -> bf16.
__global__ __launch_bounds__(256) void qkvpack_kernel(
    const float* __restrict__ x,
    const float* __restrict__ qw, const float* __restrict__ qb2,
    const float* __restrict__ qs, const float* __restrict__ qbeta,
    const float* __restrict__ kw, const float* __restrict__ kb2,
    const float* __restrict__ ks, const float* __restrict__ kbeta,
    const float* __restrict__ vw, const float* __restrict__ vb2,
    const float* __restrict__ vs, const float* __restrict__ vbeta,
    uint4* __restrict__ qpk, uint4* __restrict__ kpk, u16* __restrict__ vbf,
    const float* __restrict__ fw, u16* __restrict__ wbf)
{
    int blk = blockIdx.x;
    if (blk >= 768) {               // f_w -> bf16
        int id = (blk - 768) * 1024 + threadIdx.x;
#pragma unroll
        for (int j = 0; j < 4; ++j) { int p = id + j * 256; wbf[p] = (u16)bf16r(fw[p]); }
        return;
    }
    int type = blk >> 8;            // 0=q, 1=k, 2=v
    int sub = blk & 255;
    int nt = sub & 3, g = (sub >> 2) & 7, b = sub >> 5;
    int n = nt * 256 + threadIdx.x;
    int bh = b * 8 + g;
    const float* xp = x + ((size_t)b * C_ + g * 32) * N_ + n;
    float xv[32];
#pragma unroll
    for (int i = 0; i < 32; ++i) xv[i] = xp[(size_t)i * N_];

    const float *w, *bb, *sc, *bt;
    if (type == 0)      { w = qw; bb = qb2; sc = qs; bt = qbeta; }
    else if (type == 1) { w = kw; bb = kb2; sc = ks; bt = kbeta; }
    else                { w = vw; bb = vb2; sc = vs; bt = vbeta; }

    float y[32];
#pragma unroll
    for (int co = 0; co < 32; ++co) {
        int cg = g * 32 + co;
        float acc = 0.f;
#pragma unroll
        for (int i = 0; i < 32; ++i)
            acc = fmaf(xv[i], w[cg * 32 + i], acc);
        // INV_TEMP omitted for q: normalized below, scale cancels in cosine
        y[co] = mish_fast(sc[cg] * (acc + bb[cg]) + bt[cg]);
    }

    if (type == 2) {                // v: bf16 [bh][d][n]
#pragma unroll
        for (int co = 0; co < 32; ++co)
            vbf[((size_t)bh * 32 + co) * N_ + n] = (u16)bf16r(y[co]);
        return;
    }
    float s2 = 0.f;
#pragma unroll
    for (int d = 0; d < 32; ++d) s2 = fmaf(y[d], y[d], s2);
    float inv = __builtin_amdgcn_rsqf(fmaxf(s2, 1e-24f));
    u32 wp[16];
#pragma unroll
    for (int d = 0; d < 16; ++d)
        wp[d] = bf16r(y[2 * d] * inv) | (bf16r(y[2 * d + 1] * inv) << 16);
    uint4* dst = (type == 0 ? qpk : kpk) + ((size_t)bh * N_ + n) * 4;
#pragma unroll
    for (int j = 0; j < 4; ++j)
        dst[j] = make_uint4(wp[4 * j], wp[4 * j + 1], wp[4 * j + 2], wp[4 * j + 3]);
}

// ---------------- Kernel 2: attention (T14 reg-staged K/V, Estrin poly) ----
// Block = (bh, 64-row itile) via XCD-swizzled id, 4 waves x 16 rows.
// m in 8 chunks of 128. Per chunk: {ds_write regs (prev-issued loads),
// issue next-chunk loads, raw barrier (lgkm only, NO vmcnt drain),
// compute}. Two sweeps (rowsums, then P/am/PV). am colsums go to LDS amW
// via atomicAdd, one 4KB store per block -> 128-row ampart.
__global__ __launch_bounds__(256) void attn_kernel(
    const u16* __restrict__ qpk, const u16* __restrict__ kpk,
    const u16* __restrict__ vbf,
    u16* __restrict__ aout_bt, float* __restrict__ ampart)
{
    __shared__ __align__(16) u16 Kc[512 * 8];       // 8 KB [j=dchunk][m][8]
    __shared__ __align__(16) u16 Vc[512 * 8];       // 8 KB [d][m] granule-swz
    __shared__ __align__(16) u16 Ps[4][16 * 136];   // 17 KB, rows padded 272B
    __shared__ __align__(16) float amW[N_];         // 4 KB

    const int tid  = threadIdx.x;
    const int wave = tid >> 6, lane = tid & 63;
    const int l15 = lane & 15, lg = lane >> 4;
    // XCD-aware bijective swizzle: 1024 = 8 XCD x 128 -- the 16 blocks
    // sharing one bh's K/V land on the same XCD L2.
    const int swz = (blockIdx.x & 7) * 128 + (blockIdx.x >> 3);
    const int itile = swz & 15, bh = swz >> 4;
    const int h = bh & 7, bidx = bh >> 3;
    const int i0 = itile * 64;

    const char* ksrc = (const char*)(kpk + (size_t)bh * N_ * 32);
    const char* vsrc = (const char*)(vbf + (size_t)bh * 32 * N_);
    const char* qsrc = (const char*)(qpk + (size_t)bh * N_ * 32);

    for (int j = tid; j < N_; j += 256) amW[j] = 0.f;

    // per-thread staging granule coords (2 granules each for K and V)
    const int kj0 = tid >> 7, km0g = tid & 127;           // g = tid
    const int kj1 = (256 + tid) >> 7, km1g = (256 + tid) & 127;
    const int vd0 = tid >> 4, vg0 = tid & 15;             // g = tid
    const int vd1 = (256 + tid) >> 4, vg1 = (256 + tid) & 15;
    const size_t koff0 = (size_t)km0g * 64 + kj0 * 16;
    const size_t koff1 = (size_t)km1g * 64 + kj1 * 16;
    const size_t voff0 = (size_t)vd0 * 2048 + ((vg0 ^ (vd0 & 7)) << 4);
    const size_t voff1 = (size_t)vd1 * 2048 + ((vg1 ^ (vd1 & 7)) << 4);

    // Q frag: row = i0 + wave*16 + l15, d-chunk lg (held for whole kernel)
    bf16x8 aq = *(const bf16x8*)(qsrc + (size_t)(i0 + wave * 16 + l15) * 64 + lg * 16);

    const char* kfb = (const char*)Kc + lg * 2048 + l15 * 16;

    // ================= sweep 1: rowsums =================
    uint4 kreg0 = *(const uint4*)(ksrc + koff0);          // preload K(0)
    uint4 kreg1 = *(const uint4*)(ksrc + koff1);
    f32x2 rsL = {0.f, 0.f}, rsH = {0.f, 0.f};
    for (int ch = 0; ch < 8; ++ch) {
        *(uint4*)((char*)Kc + tid * 16)         = kreg0;  // waits vmcnt (auto)
        *(uint4*)((char*)Kc + (256 + tid) * 16) = kreg1;
        if (ch < 7) {                                     // issue next chunk
            kreg0 = *(const uint4*)(ksrc + (size_t)(ch + 1) * 8192 + koff0);
            kreg1 = *(const uint4*)(ksrc + (size_t)(ch + 1) * 8192 + koff1);
        }
        asm volatile("s_waitcnt lgkmcnt(0)" ::: "memory");
        __builtin_amdgcn_sched_barrier(0);
        __builtin_amdgcn_s_barrier();                     // no vmcnt drain
        __builtin_amdgcn_sched_barrier(0);
#pragma unroll
        for (int t = 0; t < 8; ++t) {
            bf16x8 bk = *(const bf16x8*)(kfb + t * 256);
            f32x4 cf = {0.f, 0.f, 0.f, 0.f};
            cf = mfma16(aq, bk, cf);
            rsL += fexp_poly2((f32x2){cf[0], cf[1]});
            rsH += fexp_poly2((f32x2){cf[2], cf[3]});
        }
        asm volatile("s_waitcnt lgkmcnt(0)" ::: "memory");
        __builtin_amdgcn_sched_barrier(0);
        __builtin_amdgcn_s_barrier();                     // Kc free to rewrite
        __builtin_amdgcn_sched_barrier(0);
    }
    float rinv[4];
    {
        float rr[4] = {rsL.x, rsL.y, rsH.x, rsH.y};
#pragma unroll
        for (int r = 0; r < 4; ++r) {
            float s = rr[r];
            s += __shfl_xor(s, 1); s += __shfl_xor(s, 2);
            s += __shfl_xor(s, 4); s += __shfl_xor(s, 8);
            rinv[r] = __builtin_amdgcn_rcpf(s);
        }
    }
    f32x2 rinvL = {rinv[0], rinv[1]}, rinvH = {rinv[2], rinv[3]};

    // ================= sweep 2: P(raw), am, PV =================
    f32x4 o0 = {0.f, 0.f, 0.f, 0.f}, o1 = {0.f, 0.f, 0.f, 0.f};
    char*       psw = (char*)&Ps[wave][0] + lg * 1088 + l15 * 2;
    const char* pab = (const char*)&Ps[wave][0] + l15 * 272 + lg * 16;
    const char* vfb = (const char*)Vc + l15 * 256;
    const int   vkey = l15 & 7;

    kreg0 = *(const uint4*)(ksrc + koff0);                // preload K(0),V(0)
    kreg1 = *(const uint4*)(ksrc + koff1);
    uint4 vreg0 = *(const uint4*)(vsrc + voff0);
    uint4 vreg1 = *(const uint4*)(vsrc + voff1);

    for (int ch = 0; ch < 8; ++ch) {
        int m0 = ch * 128;
        *(uint4*)((char*)Kc + tid * 16)         = kreg0;
        *(uint4*)((char*)Kc + (256 + tid) * 16) = kreg1;
        *(uint4*)((char*)Vc + tid * 16)         = vreg0;
        *(uint4*)((char*)Vc + (256 + tid) * 16) = vreg1;
        if (ch < 7) {
            kreg0 = *(const uint4*)(ksrc + (size_t)(ch + 1) * 8192 + koff0);
            kreg1 = *(const uint4*)(ksrc + (size_t)(ch + 1) * 8192 + koff1);
            vreg0 = *(const uint4*)(vsrc + (size_t)(ch + 1) * 256 + voff0);
            vreg1 = *(const uint4*)(vsrc + (size_t)(ch + 1) * 256 + voff1);
        }
        asm volatile("s_waitcnt lgkmcnt(0)" ::: "memory");
        __builtin_amdgcn_sched_barrier(0);
        __builtin_amdgcn_s_barrier();
        __builtin_amdgcn_sched_barrier(0);

#pragma unroll
        for (int t = 0; t < 8; ++t) {
            bf16x8 bk = *(const bf16x8*)(kfb + t * 256);
            f32x4 cf = {0.f, 0.f, 0.f, 0.f};
            cf = mfma16(aq, bk, cf);
            f32x2 fL = fexp_poly2((f32x2){cf[0], cf[1]});
            f32x2 fH = fexp_poly2((f32x2){cf[2], cf[3]});
            *(u16*)(psw + 0 * 272 + t * 32) = (u16)bf16r(fL.x);
            *(u16*)(psw + 1 * 272 + t * 32) = (u16)bf16r(fL.y);
            *(u16*)(psw + 2 * 272 + t * 32) = (u16)bf16r(fH.x);
            *(u16*)(psw + 3 * 272 + t * 32) = (u16)bf16r(fH.y);
            f32x2 cs2 = fL * rinvL;
            cs2 = __builtin_elementwise_fma(fH, rinvH, cs2);
            float csum = cs2.x + cs2.y;
            csum += __shfl_xor(csum, 16);
            csum += __shfl_xor(csum, 32);
            if (lane < 16) atomicAdd(&amW[m0 + t * 16 + l15], csum);
        }
        asm volatile("s_waitcnt lgkmcnt(0)" ::: "memory");  // own-wave Ps done
        __builtin_amdgcn_sched_barrier(0);
#pragma unroll
        for (int kss = 0; kss < 4; ++kss) {
            bf16x8 pa = *(const bf16x8*)(pab + kss * 64);
            const char* va = vfb + (((kss * 4 + lg) ^ vkey) << 4);
            bf16x8 v0 = *(const bf16x8*)va;
            bf16x8 v1 = *(const bf16x8*)(va + 4096);      // d = 16 + l15
            o0 = mfma16(pa, v0, o0);
            o1 = mfma16(pa, v1, o1);
        }
        asm volatile("s_waitcnt lgkmcnt(0)" ::: "memory");
        __builtin_amdgcn_sched_barrier(0);
        __builtin_amdgcn_s_barrier();                     // Kc/Vc free
        __builtin_amdgcn_sched_barrier(0);
    }
    __syncthreads();   // amW atomics complete; Ps free for cross-wave reuse

    // ---- epilogue: scale by rinv, transpose via LDS, store bf16 [b][n][c] ----
    {
        u16* oT = (u16*)Ps;                    // [64 rows][40 u16] (80B rows)
#pragma unroll
        for (int r = 0; r < 4; ++r) {
            int irow = wave * 16 + lg * 4 + r;
            oT[irow * 40 + l15]      = (u16)bf16r(o0[r] * rinv[r]);
            oT[irow * 40 + 16 + l15] = (u16)bf16r(o1[r] * rinv[r]);
        }
    }
    __syncthreads();
    {
        const u16* oT = (const u16*)Ps;
        int row = tid >> 2, c4 = tid & 3;
        uint4 val = *(const uint4*)((const char*)oT + row * 80 + c4 * 16);
        int n = i0 + row;
        int g = h * 4 + c4;
        size_t dst = ((size_t)(bidx * N_ + n) << 9) + ((size_t)((g ^ (row & 7)) << 4));
        *(uint4*)((char*)aout_bt + dst) = val;
    }
#pragma unroll
    for (int j2 = 0; j2 < 4; ++j2)
        ampart[(size_t)swz * N_ + tid + 256 * j2] = amW[tid + 256 * j2];
}

// ---------- Kernel 3: fconv (MFMA) + mish + residual; blocks 256..263: am --
__global__ __launch_bounds__(256) void fconv_kernel(
    const u16* __restrict__ aout_bt, const u16* __restrict__ wbf,
    const float* __restrict__ x,
    const float* __restrict__ fs, const float* __restrict__ fb,
    const float* __restrict__ fbeta, float* __restrict__ y,
    const float* __restrict__ ampart, float* __restrict__ outAm)
{
    __shared__ __align__(16) u16 As[32 * 256];   // 16 KB [n][c] swizzled
    __shared__ float rmn[256], rmx[256];
    const int tid = threadIdx.x;

    if (blockIdx.x >= 256) {       // ---- attention-map reduce + normalize ----
        int b = blockIdx.x - 256;
        const float* base = ampart + (size_t)b * 128 * N_;
        float s[4] = {0.f, 0.f, 0.f, 0.f};
        for (int p = 0; p < 128; ++p) {
#pragma unroll
            for (int c2 = 0; c2 < 4; ++c2)
                s[c2] += base[(size_t)p * N_ + tid + 256 * c2];
        }
        float mn = fminf(fminf(s[0], s[1]), fminf(s[2], s[3]));
        float mx = fmaxf(fmaxf(s[0], s[1]), fmaxf(s[2], s[3]));
        rmn[tid] = mn; rmx[tid] = mx;
        __syncthreads();
        for (int off = 128; off >= 1; off >>= 1) {
            if (tid < off) {
                rmn[tid] = fminf(rmn[tid], rmn[tid + off]);
                rmx[tid] = fmaxf(rmx[tid], rmx[tid + off]);
            }
            __syncthreads();
        }
        mn = rmn[0]; mx = rmx[0];
        float inv = 1.f / (mx - mn);
#pragma unroll
        for (int c2 = 0; c2 < 4; ++c2)
            outAm[(size_t)b * N_ + tid + 256 * c2] = (s[c2] - mn) * inv;
        return;
    }

    const int wave = tid >> 6, lane = tid & 63;
    const int l15 = lane & 15, lg = lane >> 4;
    const int b  = blockIdx.x >> 5;
    const int n0 = (blockIdx.x & 31) * 32;

    const char* asrc = (const char*)aout_bt + ((size_t)(b * N_ + n0) << 9);
#pragma unroll
    for (int p = 0; p < 4; ++p) {
        int g = p * 256 + wave * 64 + lane;
        __builtin_amdgcn_global_load_lds(
            (const AS1 void*)(asrc + g * 16),
            (AS3 void*)((char*)As + ((p * 256 + wave * 64) << 4)), 16, 0, 0);
    }
    __syncthreads();

    f32x4 acc[4][2];
#pragma unroll
    for (int f = 0; f < 4; ++f)
#pragma unroll
        for (int fn = 0; fn < 2; ++fn) acc[f][fn] = (f32x4){0.f, 0.f, 0.f, 0.f};

    const int cobase = wave * 64;
#pragma unroll
    for (int kk = 0; kk < 8; ++kk) {
        bf16x8 af[2];
#pragma unroll
        for (int fn = 0; fn < 2; ++fn) {
            int nf = fn * 16 + l15;
            af[fn] = *(const bf16x8*)((const char*)As + nf * 512 +
                                      (((kk * 4 + lg) ^ (nf & 7)) << 4));
        }
#pragma unroll
        for (int f = 0; f < 4; ++f) {
            bf16x8 wf = *(const bf16x8*)(wbf + (size_t)(cobase + f * 16 + l15) * 256 + kk * 32 + lg * 8);
            acc[f][0] = mfma16(wf, af[0], acc[f][0]);
            acc[f][1] = mfma16(wf, af[1], acc[f][1]);
        }
    }

#pragma unroll
    for (int f = 0; f < 4; ++f) {
#pragma unroll
        for (int r = 0; r < 4; ++r) {
            int co = cobase + f * 16 + lg * 4 + r;
            float sc = fs[co], bb = fb[co], bt = fbeta[co];
#pragma unroll
            for (int fn = 0; fn < 2; ++fn) {
                int n = n0 + fn * 16 + l15;
                size_t oid = ((size_t)(b * C_ + co) << 10) + n;
                y[oid] = mish_fast(sc * (acc[f][fn][r] + bb) + bt) + x[oid];
            }
        }
    }
}

extern "C" void kernel_launch(void* const* d_in, const int* in_sizes, int n_in,
                              void* d_out, int out_size, void* d_ws, size_t ws_size,
                              hipStream_t stream)
{
    const float* x     = (const float*)d_in[0];
    const float* q_w   = (const float*)d_in[1];
    const float* q_b   = (const float*)d_in[2];
    const float* q_s   = (const float*)d_in[3];
    const float* q_be  = (const float*)d_in[4];
    const float* k_w   = (const float*)d_in[5];
    const float* k_b   = (const float*)d_in[6];
    const float* k_s   = (const float*)d_in[7];
    const float* k_be  = (const float*)d_in[8];
    const float* v_w   = (const float*)d_in[9];
    const float* v_b   = (const float*)d_in[10];
    const float* v_s   = (const float*)d_in[11];
    const float* v_be  = (const float*)d_in[12];
    const float* f_w   = (const float*)d_in[13];
    const float* f_b   = (const float*)d_in[14];
    const float* f_s   = (const float*)d_in[15];
    const float* f_be  = (const float*)d_in[16];

    float* y_out  = (float*)d_out;                        // (8,256,32,32)
    float* am_out = (float*)d_out + (size_t)B_ * C_ * N_; // (8,32,32)

    char* w = (char*)d_ws;
    u16*   qpk     = (u16*)w;    w += (size_t)B_ * NH_ * N_ * 64;    // 4 MB
    u16*   kpk     = (u16*)w;    w += (size_t)B_ * NH_ * N_ * 64;    // 4 MB
    u16*   vbf     = (u16*)w;    w += (size_t)B_ * C_ * N_ * 2;      // 4 MB
    u16*   aout_bt = (u16*)w;    w += (size_t)B_ * N_ * C_ * 2;      // 4 MB
    float* ampart  = (float*)w;  w += (size_t)B_ * NH_ * 16 * N_ * 4;// 4 MB
    u16*   wbf     = (u16*)w;                                        // 128 KB

    qkvpack_kernel<<<832, 256, 0, stream>>>(
        x, q_w, q_b, q_s, q_be, k_w, k_b, k_s, k_be,
        v_w, v_b, v_s, v_be, (uint4*)qpk, (uint4*)kpk, vbf, f_w, wbf);

    attn_kernel<<<B_ * NH_ * 16, 256, 0, stream>>>(
        qpk, kpk, vbf, aout_bt, ampart);

    fconv_kernel<<<264, 256, 0, stream>>>(
        aout_bt, wbf, x, f_s, f_b, f_be, y_out, ampart, am_out);
}